// Round 10
// baseline (41.496 us; speedup 1.0000x reference)
//
#include <hip/hip_runtime.h>

#define BATCH 8
#define NPTS  4096
#define BLOCK 256
#define Q     4              // queries per thread
#define NQ    4              // query groups  (NQ*BLOCK*Q == NPTS)
#define NT    16             // target chunks (NT*2*PAIRS == NPTS)
#define PAIRS 128            // target pairs per chunk (4 KB SMEM set)
#define NPER  32768          // BATCH*NPTS points per cloud
#define NQTOT (2 * NPER)     // 65536 query slots (both passes)

typedef float f2 __attribute__((ext_vector_type(2)));

// ws layout:
//   float  partial[NT][65536] : per-chunk min DIST (sqrt'd)       (4 MB)
//   float4 pk4[2*32768]       : packed target PAIRS               (1 MB)
//                               [x0,x1,y0,y1] [z0,z1,w0,w1] per pair
//   double bsum[64]

// K0: pack point pairs. Pair j (0..32767): cloud = j>>14 (0=pred,1=gt),
// batch = (j&16383)>>11, pair-in-batch = j&2047.
__global__ __launch_bounds__(256) void pack_kernel(
    const float* __restrict__ pred, const float* __restrict__ gt,
    float4* __restrict__ pk4)
{
    const int j  = blockIdx.x * 256 + threadIdx.x;
    const float* src = (j < 16384) ? pred : gt;
    const int pj = j & 16383;
    const float* t = src + (size_t)(pj >> 11) * (NPTS * 3)
                         + (size_t)(pj & 2047) * 6;
    const float x0 = t[0], y0 = t[1], z0 = t[2];
    const float x1 = t[3], y1 = t[4], z1 = t[5];
    pk4[2 * j]     = make_float4(x0, x1, y0, y1);
    pk4[2 * j + 1] = make_float4(z0, z1,
                                 fmaf(x0, x0, fmaf(y0, y0, z0 * z0)),
                                 fmaf(x1, x1, fmaf(y1, y1, z1 * z1)));
}

// K1: grid (NQ, NT, 16) = 1024 blocks, NO LDS. Each thread owns Q=4 queries;
// target pairs are read via wave-uniform loads from pk4 (-> s_load, SGPR
// broadcast). Per pair per query: 3 v_pk_fma_f32 + 1 v_min3_f32; the gw VGPR
// copy amortizes over Q. Writes sqrt'd chunk-min to private partial slice.
__global__ __launch_bounds__(BLOCK) void chamfer_min_kernel(
    const float* __restrict__ pred, const float* __restrict__ gt,
    const float4* __restrict__ pk4, float* __restrict__ partial)
{
    const int z    = blockIdx.z;                      // pass*8 + b
    const int b    = z & 7;
    const int pass = z >> 3;
    const float* query = (pass ? gt : pred) + (size_t)b * NPTS * 3;

    const int tid   = threadIdx.x;
    const int qbase = blockIdx.x * (BLOCK * Q);

    f2 nx[Q], ny[Q], nz[Q];
    float p2[Q], mn[Q];
#pragma unroll
    for (int i = 0; i < Q; ++i) {
        const float* qp = query + (size_t)(qbase + i * BLOCK + tid) * 3;
        const float x = qp[0], y = qp[1], zz = qp[2];
        nx[i] = (f2){-2.0f * x, -2.0f * x};
        ny[i] = (f2){-2.0f * y, -2.0f * y};
        nz[i] = (f2){-2.0f * zz, -2.0f * zz};
        p2[i] = fmaf(x, x, fmaf(y, y, zz * zz));
        mn[i] = 3.0e38f;
    }

    // wave-uniform target-pair pointer for this chunk
    const float4* tp = pk4 + 2 * ((size_t)(1 - pass) * 16384
                                  + b * 2048 + blockIdx.y * PAIRS);

#pragma unroll 4
    for (int j = 0; j < PAIRS; ++j) {
        const float4 a  = tp[2 * j];                  // (x0,x1,y0,y1) uniform
        const float4 bb = tp[2 * j + 1];              // (z0,z1,w0,w1) uniform
        const f2 gx = {a.x, a.y};
        const f2 gy = {a.z, a.w};
        const f2 gz = {bb.x, bb.y};
        const f2 gw = {bb.z, bb.w};                   // (g2_0, g2_1)
#pragma unroll
        for (int i = 0; i < Q; ++i) {
            f2 d = __builtin_elementwise_fma(nx[i], gx, gw);
            d = __builtin_elementwise_fma(ny[i], gy, d);
            d = __builtin_elementwise_fma(nz[i], gz, d);
            mn[i] = fminf(mn[i], fminf(d.x, d.y));    // -> v_min3_f32
        }
    }

    float* dst = partial + (size_t)blockIdx.y * NQTOT
               + (size_t)pass * NPER + (size_t)b * NPTS + qbase;
#pragma unroll
    for (int i = 0; i < Q; ++i) {
        dst[i * BLOCK + tid] = sqrtf(fmaxf(p2[i] + mn[i], 0.0f));
    }
}

// K2: 64 blocks x 1024. Thread j: min over NT chunk-partials (sqrt'd),
// deterministic LDS tree-sum in double -> bsum[block].
__global__ __launch_bounds__(1024) void reduce1_kernel(
    const float* __restrict__ partial, double* __restrict__ bsum)
{
    const int tid = threadIdx.x;
    const int j   = blockIdx.x * 1024 + tid;          // query slot 0..65535

    float m = 3.0e38f;
#pragma unroll 4
    for (int c = 0; c < NT; c += 2) {
        const float a0 = partial[(size_t)c * NQTOT + j];
        const float a1 = partial[(size_t)(c + 1) * NQTOT + j];
        m = fminf(m, fminf(a0, a1));
    }

    __shared__ double sd[1024];
    sd[tid] = (double)m;
    __syncthreads();
    for (int off = 512; off > 0; off >>= 1) {
        if (tid < off) sd[tid] += sd[tid + off];
        __syncthreads();
    }
    if (tid == 0) bsum[blockIdx.x] = sd[0];
}

// K3: one wave sums the 64 block sums (deterministic shuffle tree).
__global__ __launch_bounds__(64) void reduce2_kernel(
    const double* __restrict__ bsum, float* __restrict__ out)
{
    double v = bsum[threadIdx.x];
#pragma unroll
    for (int off = 32; off > 0; off >>= 1) {
        v += __shfl_down(v, off);
    }
    if (threadIdx.x == 0) out[0] = (float)(v / (double)NPER);
}

extern "C" void kernel_launch(void* const* d_in, const int* in_sizes, int n_in,
                              void* d_out, int out_size, void* d_ws, size_t ws_size,
                              hipStream_t stream) {
    const float* pred = (const float*)d_in[0];
    const float* gt   = (const float*)d_in[1];

    float*  partial = (float*)d_ws;                          // 4 MB
    float4* pk4     = (float4*)(partial + (size_t)NT * NQTOT); // 1 MB
    double* bsum    = (double*)(pk4 + 2 * 32768);

    pack_kernel<<<32768 / 256, 256, 0, stream>>>(pred, gt, pk4);

    dim3 grid(NQ, NT, 2 * BATCH);
    chamfer_min_kernel<<<grid, BLOCK, 0, stream>>>(pred, gt, pk4, partial);

    reduce1_kernel<<<NQTOT / 1024, 1024, 0, stream>>>(partial, bsum);
    reduce2_kernel<<<1, 64, 0, stream>>>(bsum, (float*)d_out);
}

// Round 11
// 39.747 us; speedup vs baseline: 1.0440x; 1.0440x over previous
//
#include <hip/hip_runtime.h>

#define BATCH 8
#define NPTS  4096
#define BLOCK 256
#define Q     8              // query points per thread
#define NQ    2              // query groups   (NQ*BLOCK*Q == NPTS)
#define NT    32             // target chunks  (NT*CHUNK   == NPTS)
#define CHUNK 128            // targets staged in LDS per block
#define NPAIR (CHUNK / 2)    // 64 target PAIRS in LDS
#define NPER  32768          // BATCH*NPTS points per cloud
#define NQTOT (2 * NPER)     // 65536 query slots (both passes)

typedef float f2 __attribute__((ext_vector_type(2)));

// ws layout:
//   float  partial[NT][65536]: per-chunk min DIST (already sqrt'd)   (8 MB)
//   double bsum[64]          : per-block partial sums from reduce1

// K1: grid (NQ, NT, 16) = 1024 blocks -> 4 blocks/CU, 4 waves/SIMD.
// Each thread owns Q=8 queries; block stages CHUNK=128 targets in LDS as
// float2-pairs [(x0,x1,y0,y1),(z0,z1,w0,w1)]. Inner loop: 1-deep register
// prefetch of the next pair, then 3 v_pk_fma_f32 + 1 v_min3_f32 per query
// (2 VALU instr per target). Writes sqrt'd chunk-min to a private partial
// slice with plain coalesced stores. No atomics, no init, no fences.
__global__ __launch_bounds__(BLOCK, 4) void chamfer_min_kernel(
    const float* __restrict__ pred, const float* __restrict__ gt,
    float* __restrict__ partial)
{
    const int z    = blockIdx.z;                      // pass*8 + b
    const int b    = z & 7;
    const int pass = z >> 3;
    const float* query  = (pass ? gt : pred) + (size_t)b * NPTS * 3;
    const float* target = (pass ? pred : gt) + (size_t)b * NPTS * 3;

    __shared__ float4 sA[NPAIR];                      // (x0,x1,y0,y1)
    __shared__ float4 sB[NPAIR];                      // (z0,z1,w0,w1)

    const int tid   = threadIdx.x;
    const int qbase = blockIdx.x * (BLOCK * Q);
    const int c0    = blockIdx.y * CHUNK;

    if (tid < NPAIR) {
        const float* t0 = target + (size_t)(c0 + 2 * tid) * 3;
        const float x0 = t0[0], y0 = t0[1], z0 = t0[2];
        const float x1 = t0[3], y1 = t0[4], z1 = t0[5];
        const float w0 = fmaf(x0, x0, fmaf(y0, y0, z0 * z0));
        const float w1 = fmaf(x1, x1, fmaf(y1, y1, z1 * z1));
        sA[tid] = make_float4(x0, x1, y0, y1);
        sB[tid] = make_float4(z0, z1, w0, w1);
    }

    f2 nx[Q], ny[Q], nz[Q];
    float p2[Q], mn[Q];
#pragma unroll
    for (int i = 0; i < Q; ++i) {
        const float* qp = query + (size_t)(qbase + i * BLOCK + tid) * 3;
        const float x = qp[0], y = qp[1], zz = qp[2];
        nx[i] = (f2){-2.0f * x, -2.0f * x};
        ny[i] = (f2){-2.0f * y, -2.0f * y};
        nz[i] = (f2){-2.0f * zz, -2.0f * zz};
        p2[i] = fmaf(x, x, fmaf(y, y, zz * zz));
        mn[i] = 3.0e38f;
    }
    __syncthreads();

    float4 a  = sA[0];
    float4 bb = sB[0];
#pragma unroll 4
    for (int j = 0; j < NPAIR; ++j) {
        const float4 an = sA[(j + 1) & (NPAIR - 1)];  // prefetch next pair
        const float4 bn = sB[(j + 1) & (NPAIR - 1)];
        const f2 gx = {a.x, a.y};
        const f2 gy = {a.z, a.w};
        const f2 gz = {bb.x, bb.y};
        const f2 gw = {bb.z, bb.w};                   // (g2_0, g2_1)
#pragma unroll
        for (int i = 0; i < Q; ++i) {
            f2 d = __builtin_elementwise_fma(gx, nx[i], gw);
            d = __builtin_elementwise_fma(gy, ny[i], d);
            d = __builtin_elementwise_fma(gz, nz[i], d);
            mn[i] = fminf(mn[i], fminf(d.x, d.y));    // -> v_min3_f32
        }
        a = an; bb = bn;
    }

    float* dst = partial + (size_t)blockIdx.y * NQTOT
               + (size_t)pass * NPER + (size_t)b * NPTS + qbase;
#pragma unroll
    for (int i = 0; i < Q; ++i) {
        dst[i * BLOCK + tid] = sqrtf(fmaxf(p2[i] + mn[i], 0.0f));
    }
}

// K2: 64 blocks x 1024. Thread j: min over NT chunk-partials (already sqrt'd),
// deterministic LDS tree-sum in double -> bsum[block].
__global__ __launch_bounds__(1024) void reduce1_kernel(
    const float* __restrict__ partial, double* __restrict__ bsum)
{
    const int tid = threadIdx.x;
    const int j   = blockIdx.x * 1024 + tid;          // query slot 0..65535

    float m = 3.0e38f;
#pragma unroll 4
    for (int c = 0; c < NT; c += 2) {
        const float a0 = partial[(size_t)c * NQTOT + j];
        const float a1 = partial[(size_t)(c + 1) * NQTOT + j];
        m = fminf(m, fminf(a0, a1));
    }

    __shared__ double sd[1024];
    sd[tid] = (double)m;
    __syncthreads();
    for (int off = 512; off > 0; off >>= 1) {
        if (tid < off) sd[tid] += sd[tid + off];
        __syncthreads();
    }
    if (tid == 0) bsum[blockIdx.x] = sd[0];
}

// K3: one wave sums the 64 block sums (deterministic shuffle tree).
__global__ __launch_bounds__(64) void reduce2_kernel(
    const double* __restrict__ bsum, float* __restrict__ out)
{
    double v = bsum[threadIdx.x];
#pragma unroll
    for (int off = 32; off > 0; off >>= 1) {
        v += __shfl_down(v, off);
    }
    if (threadIdx.x == 0) out[0] = (float)(v / (double)NPER);
}

extern "C" void kernel_launch(void* const* d_in, const int* in_sizes, int n_in,
                              void* d_out, int out_size, void* d_ws, size_t ws_size,
                              hipStream_t stream) {
    const float* pred = (const float*)d_in[0];
    const float* gt   = (const float*)d_in[1];

    float*  partial = (float*)d_ws;                         // 8 MB
    double* bsum    = (double*)(partial + (size_t)NT * NQTOT);

    dim3 grid(NQ, NT, 2 * BATCH);
    chamfer_min_kernel<<<grid, BLOCK, 0, stream>>>(pred, gt, partial);

    reduce1_kernel<<<NQTOT / 1024, 1024, 0, stream>>>(partial, bsum);
    reduce2_kernel<<<1, 64, 0, stream>>>(bsum, (float*)d_out);
}

// Round 12
// 39.105 us; speedup vs baseline: 1.0611x; 1.0164x over previous
//
#include <hip/hip_runtime.h>

#define BATCH 8
#define NPTS  4096
#define BLOCK 256
#define Q     8              // query points per thread
#define NQ    2              // query groups   (NQ*BLOCK*Q == NPTS)
#define NT    16             // target chunks  (NT*CHUNK   == NPTS)
#define CHUNK 256            // targets staged in LDS per block
#define NPAIR (CHUNK / 2)    // 128 target PAIRS in LDS
#define NPER  32768          // BATCH*NPTS points per cloud
#define NQTOT (2 * NPER)     // 65536 query slots (both passes)

typedef float f2 __attribute__((ext_vector_type(2)));

// ws layout:
//   float  partial[NT][65536]: per-chunk min DIST (already sqrt'd)   (4 MB)
//   float4 pk[65536]         : packed [x,y,z,|p|^2]; pred then gt    (1 MB)
//   double bsum[64]          : per-block partial sums from reduce1

// K0: coalesced pack: point j -> float4 (x,y,z,|p|^2).
__global__ __launch_bounds__(256) void pack_kernel(
    const float* __restrict__ pred, const float* __restrict__ gt,
    float4* __restrict__ pk)
{
    const int j = blockIdx.x * 256 + threadIdx.x;     // 0..65535
    const float* src = (j < NPER) ? pred : gt;
    const float* p = src + (size_t)(j & (NPER - 1)) * 3;
    const float x = p[0], y = p[1], z = p[2];
    pk[j] = make_float4(x, y, z, fmaf(x, x, fmaf(y, y, z * z)));
}

// K1: grid (NQ, NT, 16) = 512 blocks (R8 geometry). Coalesced float4 query
// loads; block stages CHUNK=256 targets in LDS as pair-packed
// [(x0,x1,y0,y1),(z0,z1,w0,w1)]. Per target-pair per query:
// 3 v_pk_fma_f32 + 1 v_min3_f32 (2 VALU instr per target). Writes sqrt'd
// chunk-min to a private partial slice. No atomics, no init, no fences.
__global__ __launch_bounds__(BLOCK) void chamfer_min_kernel(
    const float4* __restrict__ pk, float* __restrict__ partial)
{
    const int z    = blockIdx.z;                      // pass*8 + b
    const int b    = z & 7;
    const int pass = z >> 3;
    const float4* query  = pk + (pass ? NPER : 0) + b * NPTS;
    const float4* target = pk + (pass ? 0 : NPER) + b * NPTS;

    __shared__ float4 sA[NPAIR];                      // (x0,x1,y0,y1)
    __shared__ float4 sB[NPAIR];                      // (z0,z1,w0,w1)

    const int tid   = threadIdx.x;
    const int qbase = blockIdx.x * (BLOCK * Q);
    const int c0    = blockIdx.y * CHUNK;

    if (tid < NPAIR) {
        const float4 t0 = target[c0 + 2 * tid];
        const float4 t1 = target[c0 + 2 * tid + 1];
        sA[tid] = make_float4(t0.x, t1.x, t0.y, t1.y);
        sB[tid] = make_float4(t0.z, t1.z, t0.w, t1.w);
    }

    f2 nx[Q], ny[Q], nz[Q];
    float p2[Q], mn[Q];
#pragma unroll
    for (int i = 0; i < Q; ++i) {
        const float4 qf = query[qbase + i * BLOCK + tid];   // coalesced b128
        nx[i] = (f2){-2.0f * qf.x, -2.0f * qf.x};
        ny[i] = (f2){-2.0f * qf.y, -2.0f * qf.y};
        nz[i] = (f2){-2.0f * qf.z, -2.0f * qf.z};
        p2[i] = qf.w;
        mn[i] = 3.0e38f;
    }
    __syncthreads();

#pragma unroll 2
    for (int j = 0; j < NPAIR; ++j) {
        const float4 a  = sA[j];
        const float4 bb = sB[j];
        const f2 gx = {a.x, a.y};
        const f2 gy = {a.z, a.w};
        const f2 gz = {bb.x, bb.y};
        const f2 gw = {bb.z, bb.w};                   // (g2_0, g2_1)
#pragma unroll
        for (int i = 0; i < Q; ++i) {
            f2 d = __builtin_elementwise_fma(gx, nx[i], gw);
            d = __builtin_elementwise_fma(gy, ny[i], d);
            d = __builtin_elementwise_fma(gz, nz[i], d);
            mn[i] = fminf(mn[i], fminf(d.x, d.y));    // -> v_min3_f32
        }
    }

    float* dst = partial + (size_t)blockIdx.y * NQTOT + (size_t)z * NPTS + qbase;
#pragma unroll
    for (int i = 0; i < Q; ++i) {
        dst[i * BLOCK + tid] = sqrtf(fmaxf(p2[i] + mn[i], 0.0f));
    }
}

// K2: 64 blocks x 1024. Thread j: min over NT chunk-partials (already sqrt'd),
// deterministic LDS tree-sum in double -> bsum[block].
__global__ __launch_bounds__(1024) void reduce1_kernel(
    const float* __restrict__ partial, double* __restrict__ bsum)
{
    const int tid = threadIdx.x;
    const int j   = blockIdx.x * 1024 + tid;          // query slot 0..65535

    float m = 3.0e38f;
#pragma unroll
    for (int c = 0; c < NT; c += 2) {
        const float a0 = partial[(size_t)c * NQTOT + j];
        const float a1 = partial[(size_t)(c + 1) * NQTOT + j];
        m = fminf(m, fminf(a0, a1));
    }

    __shared__ double sd[1024];
    sd[tid] = (double)m;
    __syncthreads();
    for (int off = 512; off > 0; off >>= 1) {
        if (tid < off) sd[tid] += sd[tid + off];
        __syncthreads();
    }
    if (tid == 0) bsum[blockIdx.x] = sd[0];
}

// K3: one wave sums the 64 block sums (deterministic shuffle tree).
__global__ __launch_bounds__(64) void reduce2_kernel(
    const double* __restrict__ bsum, float* __restrict__ out)
{
    double v = bsum[threadIdx.x];
#pragma unroll
    for (int off = 32; off > 0; off >>= 1) {
        v += __shfl_down(v, off);
    }
    if (threadIdx.x == 0) out[0] = (float)(v / (double)NPER);
}

extern "C" void kernel_launch(void* const* d_in, const int* in_sizes, int n_in,
                              void* d_out, int out_size, void* d_ws, size_t ws_size,
                              hipStream_t stream) {
    const float* pred = (const float*)d_in[0];
    const float* gt   = (const float*)d_in[1];

    float*  partial = (float*)d_ws;                             // 4 MB
    float4* pk      = (float4*)(partial + (size_t)NT * NQTOT);  // 1 MB
    double* bsum    = (double*)(pk + NQTOT);

    pack_kernel<<<NQTOT / 256, 256, 0, stream>>>(pred, gt, pk);

    dim3 grid(NQ, NT, 2 * BATCH);
    chamfer_min_kernel<<<grid, BLOCK, 0, stream>>>(pk, partial);

    reduce1_kernel<<<NQTOT / 1024, 1024, 0, stream>>>(partial, bsum);
    reduce2_kernel<<<1, 64, 0, stream>>>(bsum, (float*)d_out);
}

// Round 13
// 36.806 us; speedup vs baseline: 1.1274x; 1.0625x over previous
//
#include <hip/hip_runtime.h>

#define BATCH 8
#define NPTS  4096
#define BLOCK 256
#define Q     16             // query points per thread (BLOCK*Q == NPTS, NQ==1)
#define NT    32             // target chunks  (NT*CHUNK == NPTS)
#define CHUNK 128            // targets staged in LDS per block
#define NPAIR (CHUNK / 2)    // 64 target PAIRS in LDS
#define NPER  32768          // BATCH*NPTS points per cloud
#define NQTOT (2 * NPER)     // 65536 query slots (both passes)

typedef float f2 __attribute__((ext_vector_type(2)));

// ws layout:
//   float partial[NT][65536]: per-chunk min DIST (already sqrt'd)   (8 MB)

// K1: grid (1, NT, 16) = 512 blocks -> 2 blocks/CU, 2 waves/SIMD.
// Each thread owns Q=16 queries (i*BLOCK+tid); block stages CHUNK=128 targets
// in LDS as float2-pairs [(x0,x1,y0,y1),(z0,z1,w0,w1)]. Per target-pair per
// query: 3 v_pk_fma_f32 + 1 v_min3_f32 (2 VALU instr per target). Writes
// sqrt'd chunk-min to a private partial slice. Thread (0,0,0) zeroes out[0]
// for the next kernel's atomicAdd. No atomics here, no init, no fences.
__global__ __launch_bounds__(BLOCK) void chamfer_min_kernel(
    const float* __restrict__ pred, const float* __restrict__ gt,
    float* __restrict__ partial, float* __restrict__ out)
{
    const int z    = blockIdx.z;                      // pass*8 + b
    const int b    = z & 7;
    const int pass = z >> 3;
    const float* query  = (pass ? gt : pred) + (size_t)b * NPTS * 3;
    const float* target = (pass ? pred : gt) + (size_t)b * NPTS * 3;

    __shared__ float4 sA[NPAIR];                      // (x0,x1,y0,y1)
    __shared__ float4 sB[NPAIR];                      // (z0,z1,w0,w1)

    const int tid = threadIdx.x;
    const int c0  = blockIdx.y * CHUNK;

    if (blockIdx.y == 0 && z == 0 && tid == 0) out[0] = 0.0f;

    if (tid < NPAIR) {
        const float* t0 = target + (size_t)(c0 + 2 * tid) * 3;
        const float x0 = t0[0], y0 = t0[1], z0 = t0[2];
        const float x1 = t0[3], y1 = t0[4], z1 = t0[5];
        const float w0 = fmaf(x0, x0, fmaf(y0, y0, z0 * z0));
        const float w1 = fmaf(x1, x1, fmaf(y1, y1, z1 * z1));
        sA[tid] = make_float4(x0, x1, y0, y1);
        sB[tid] = make_float4(z0, z1, w0, w1);
    }

    f2 nx[Q], ny[Q], nz[Q];
    float p2[Q], mn[Q];
#pragma unroll
    for (int i = 0; i < Q; ++i) {
        const float* qp = query + (size_t)(i * BLOCK + tid) * 3;
        const float x = qp[0], y = qp[1], zz = qp[2];
        nx[i] = (f2){-2.0f * x, -2.0f * x};
        ny[i] = (f2){-2.0f * y, -2.0f * y};
        nz[i] = (f2){-2.0f * zz, -2.0f * zz};
        p2[i] = fmaf(x, x, fmaf(y, y, zz * zz));
        mn[i] = 3.0e38f;
    }
    __syncthreads();

#pragma unroll 2
    for (int j = 0; j < NPAIR; ++j) {
        const float4 a  = sA[j];
        const float4 bb = sB[j];
        const f2 gx = {a.x, a.y};
        const f2 gy = {a.z, a.w};
        const f2 gz = {bb.x, bb.y};
        const f2 gw = {bb.z, bb.w};                   // (g2_0, g2_1)
#pragma unroll
        for (int i = 0; i < Q; ++i) {
            f2 d = __builtin_elementwise_fma(gx, nx[i], gw);
            d = __builtin_elementwise_fma(gy, ny[i], d);
            d = __builtin_elementwise_fma(gz, nz[i], d);
            mn[i] = fminf(mn[i], fminf(d.x, d.y));    // -> v_min3_f32
        }
    }

    float* dst = partial + (size_t)blockIdx.y * NQTOT + (size_t)z * NPTS;
#pragma unroll
    for (int i = 0; i < Q; ++i) {
        dst[i * BLOCK + tid] = sqrtf(fmaxf(p2[i] + mn[i], 0.0f));
    }
}

// K2: 64 blocks x 1024. Thread j: min over NT chunk-partials (already
// sqrt'd), deterministic per-block LDS tree-sum in double, then ONE
// atomicAdd(float) per block of (block_sum / 32768) into out[0].
// 64 float adds at ~2.4 magnitude -> ordering jitter ~1e-6 << threshold.
__global__ __launch_bounds__(1024) void reduce_kernel(
    const float* __restrict__ partial, float* __restrict__ out)
{
    const int tid = threadIdx.x;
    const int j   = blockIdx.x * 1024 + tid;          // query slot 0..65535

    float m = 3.0e38f;
#pragma unroll 4
    for (int c = 0; c < NT; c += 2) {
        const float a0 = partial[(size_t)c * NQTOT + j];
        const float a1 = partial[(size_t)(c + 1) * NQTOT + j];
        m = fminf(m, fminf(a0, a1));
    }

    __shared__ double sd[1024];
    sd[tid] = (double)m;
    __syncthreads();
    for (int off = 512; off > 0; off >>= 1) {
        if (tid < off) sd[tid] += sd[tid + off];
        __syncthreads();
    }
    if (tid == 0) {
        atomicAdd(out, (float)(sd[0] / (double)NPER));
    }
}

extern "C" void kernel_launch(void* const* d_in, const int* in_sizes, int n_in,
                              void* d_out, int out_size, void* d_ws, size_t ws_size,
                              hipStream_t stream) {
    const float* pred = (const float*)d_in[0];
    const float* gt   = (const float*)d_in[1];

    float* partial = (float*)d_ws;                    // 8 MB
    float* out     = (float*)d_out;

    dim3 grid(1, NT, 2 * BATCH);
    chamfer_min_kernel<<<grid, BLOCK, 0, stream>>>(pred, gt, partial, out);

    reduce_kernel<<<NQTOT / 1024, 1024, 0, stream>>>(partial, out);
}

// Round 14
// 35.539 us; speedup vs baseline: 1.1676x; 1.0356x over previous
//
#include <hip/hip_runtime.h>

#define BATCH 8
#define NPTS  4096
#define BLOCK 256
#define Q     16             // query points per thread (BLOCK*Q == NPTS, NQ==1)
#define NT    32             // target chunks  (NT*CHUNK == NPTS)
#define CHUNK 128            // targets staged in LDS per block
#define NPAIR (CHUNK / 2)    // 64 target PAIRS in LDS
#define NPER  32768          // BATCH*NPTS points per cloud
#define NQTOT (2 * NPER)     // 65536 query slots (both passes)

typedef float f2 __attribute__((ext_vector_type(2)));

// Force VOP3P packed fp32 FMA (double-rate): d = a*b + c on both halves.
static __device__ __forceinline__ f2 pk_fma(f2 a, f2 b, f2 c) {
    f2 d;
    asm("v_pk_fma_f32 %0, %1, %2, %3" : "=v"(d) : "v"(a), "v"(b), "v"(c));
    return d;
}
// Force single-instruction 3-input min.
static __device__ __forceinline__ float min3f(float a, float b, float c) {
    float d;
    asm("v_min3_f32 %0, %1, %2, %3" : "=v"(d) : "v"(a), "v"(b), "v"(c));
    return d;
}

// ws layout:
//   float partial[NT][65536]: per-chunk min DIST (already sqrt'd)   (8 MB)

// K1: grid (1, NT, 16) = 512 blocks -> 2 blocks/CU, 2 waves/SIMD.
// Each thread owns Q=16 queries (i*BLOCK+tid); block stages CHUNK=128 targets
// in LDS as float2-pairs [(x0,x1,y0,y1),(z0,z1,w0,w1)]. Per target-pair per
// query: 3 v_pk_fma_f32 + 1 v_min3_f32 (2 VALU instr per target, enforced by
// inline asm). Writes sqrt'd chunk-min to a private partial slice. Thread
// (0,0,0) zeroes out[0] for the next kernel's atomicAdd.
__global__ __launch_bounds__(BLOCK) void chamfer_min_kernel(
    const float* __restrict__ pred, const float* __restrict__ gt,
    float* __restrict__ partial, float* __restrict__ out)
{
    const int z    = blockIdx.z;                      // pass*8 + b
    const int b    = z & 7;
    const int pass = z >> 3;
    const float* query  = (pass ? gt : pred) + (size_t)b * NPTS * 3;
    const float* target = (pass ? pred : gt) + (size_t)b * NPTS * 3;

    __shared__ float4 sA[NPAIR];                      // (x0,x1,y0,y1)
    __shared__ float4 sB[NPAIR];                      // (z0,z1,w0,w1)

    const int tid = threadIdx.x;
    const int c0  = blockIdx.y * CHUNK;

    if (blockIdx.y == 0 && z == 0 && tid == 0) out[0] = 0.0f;

    if (tid < NPAIR) {
        const float* t0 = target + (size_t)(c0 + 2 * tid) * 3;
        const float x0 = t0[0], y0 = t0[1], z0 = t0[2];
        const float x1 = t0[3], y1 = t0[4], z1 = t0[5];
        const float w0 = fmaf(x0, x0, fmaf(y0, y0, z0 * z0));
        const float w1 = fmaf(x1, x1, fmaf(y1, y1, z1 * z1));
        sA[tid] = make_float4(x0, x1, y0, y1);
        sB[tid] = make_float4(z0, z1, w0, w1);
    }

    f2 nx[Q], ny[Q], nz[Q];
    float p2[Q], mn[Q];
#pragma unroll
    for (int i = 0; i < Q; ++i) {
        const float* qp = query + (size_t)(i * BLOCK + tid) * 3;
        const float x = qp[0], y = qp[1], zz = qp[2];
        nx[i] = (f2){-2.0f * x, -2.0f * x};
        ny[i] = (f2){-2.0f * y, -2.0f * y};
        nz[i] = (f2){-2.0f * zz, -2.0f * zz};
        p2[i] = fmaf(x, x, fmaf(y, y, zz * zz));
        mn[i] = 3.0e38f;
    }
    __syncthreads();

#pragma unroll 2
    for (int j = 0; j < NPAIR; ++j) {
        const float4 a  = sA[j];
        const float4 bb = sB[j];
        const f2 gx = {a.x, a.y};
        const f2 gy = {a.z, a.w};
        const f2 gz = {bb.x, bb.y};
        const f2 gw = {bb.z, bb.w};                   // (g2_0, g2_1)
#pragma unroll
        for (int i = 0; i < Q; ++i) {
            f2 d = pk_fma(gx, nx[i], gw);
            d = pk_fma(gy, ny[i], d);
            d = pk_fma(gz, nz[i], d);
            mn[i] = min3f(mn[i], d.x, d.y);
        }
    }

    float* dst = partial + (size_t)blockIdx.y * NQTOT + (size_t)z * NPTS;
#pragma unroll
    for (int i = 0; i < Q; ++i) {
        dst[i * BLOCK + tid] = sqrtf(fmaxf(p2[i] + mn[i], 0.0f));
    }
}

// K2: 64 blocks x 1024. Thread j: min over NT chunk-partials (already
// sqrt'd), deterministic per-block LDS tree-sum in double, then ONE
// atomicAdd(float) per block of (block_sum / 32768) into out[0].
__global__ __launch_bounds__(1024) void reduce_kernel(
    const float* __restrict__ partial, float* __restrict__ out)
{
    const int tid = threadIdx.x;
    const int j   = blockIdx.x * 1024 + tid;          // query slot 0..65535

    float m = 3.0e38f;
#pragma unroll 4
    for (int c = 0; c < NT; c += 2) {
        const float a0 = partial[(size_t)c * NQTOT + j];
        const float a1 = partial[(size_t)(c + 1) * NQTOT + j];
        m = fminf(m, fminf(a0, a1));
    }

    __shared__ double sd[1024];
    sd[tid] = (double)m;
    __syncthreads();
    for (int off = 512; off > 0; off >>= 1) {
        if (tid < off) sd[tid] += sd[tid + off];
        __syncthreads();
    }
    if (tid == 0) {
        atomicAdd(out, (float)(sd[0] / (double)NPER));
    }
}

extern "C" void kernel_launch(void* const* d_in, const int* in_sizes, int n_in,
                              void* d_out, int out_size, void* d_ws, size_t ws_size,
                              hipStream_t stream) {
    const float* pred = (const float*)d_in[0];
    const float* gt   = (const float*)d_in[1];

    float* partial = (float*)d_ws;                    // 8 MB
    float* out     = (float*)d_out;

    dim3 grid(1, NT, 2 * BATCH);
    chamfer_min_kernel<<<grid, BLOCK, 0, stream>>>(pred, gt, partial, out);

    reduce_kernel<<<NQTOT / 1024, 1024, 0, stream>>>(partial, out);
}